// Round 7
// baseline (212.913 us; speedup 1.0000x reference)
//
#include <hip/hip_runtime.h>
#include <utility>

#define NQ   7
#define DIM  128
#define HALF 64            // state elements per lane (2 lanes per row)
#define RPB  32            // rows per block (1 wave)

// static_for: constexpr indices in initial IR -> first SROA scalarizes arrays.
template<class F, int... I>
__device__ __forceinline__ void static_for_impl(F&& f, std::integer_sequence<int, I...>) {
    (f(std::integral_constant<int, I>{}), ...);
}
template<int N, class F>
__device__ __forceinline__ void static_for(F&& f) {
    static_for_impl(static_cast<F&&>(f), std::make_integer_sequence<int, N>{});
}

// swap with adjacent lane (2t <-> 2t+1): v_mov_b32 dpp quad_perm:[1,0,3,2]
__device__ __forceinline__ float swap_adj(float x) {
    int v = __builtin_amdgcn_update_dpp(0, __builtin_bit_cast(int, x),
                                        0xB1 /*quad_perm [1,0,3,2]*/,
                                        0xF, 0xF, true);
    return __builtin_bit_cast(float, v);
}

// 2 lanes per row: lane 2t+h owns elements [h*64, h*64+64) of row t.
// R6 fix: LDS 16.9 KB capped occupancy at 9 blocks/CU (19% meas). Stage the
// 32x32-f4 tile in TWO 16-row chunks through an 8448 B buffer -> 16+ blocks/CU.
// Both chunks' global loads issue up-front; chunk1 stays in flight (vmcnt>0)
// across chunk0's LDS round-trip. 1-wave workgroup: barriers lower to waitcnt.
// CZ algebra: layer-2 CZ squared away by probs; layer-1 CZ local signs fold
// into layer-2 q0 operand fnegs (compile-time, free); cross term (-1)^(b5 h)
// commutes past q0..q4 and folds into layer-2 q5 coefficients (2 muls).
__global__ __launch_bounds__(64, 2)
void qnat_kernel(const float* __restrict__ embed,
                 const float* __restrict__ theta,
                 float* __restrict__ out)
{
    __shared__ float4 tile[16 * 33];                   // 8448 B
    const int lane = threadIdx.x;                      // 0..63
    const int t = lane >> 1;                           // row within block
    const int h = lane & 1;                            // half of the row
    const float hs = h ? -1.f : 1.f;
    const float4* __restrict__ g4 =
        reinterpret_cast<const float4*>(embed) + (size_t)blockIdx.x * (RPB * 32);

    // ---- issue ALL 16 coalesced 1KB loads up-front (full lines) ----
    float4 A[8], B[8];
    static_for<8>([&](auto J) {                        // rows 0..15
        constexpr int j = J.value;
        A[j] = g4[j * 64 + lane];
    });
    static_for<8>([&](auto J) {                        // rows 16..31
        constexpr int j = J.value;
        B[j] = g4[512 + j * 64 + lane];
    });

    float st[HALF];

    // ---- chunk 0: rows 0..15 ----
    static_for<8>([&](auto J) {                        // waits vmcnt for A only
        constexpr int j = J.value;
        tile[(2 * j + (lane >> 5)) * 33 + (lane & 31)] = A[j];
    });
    __syncthreads();
    if (t < 16) {
        static_for<16>([&](auto J) {
            constexpr int j = J.value;
            const float4 v = tile[t * 33 + h * 16 + j];
            st[4 * j + 0] = v.x; st[4 * j + 1] = v.y;
            st[4 * j + 2] = v.z; st[4 * j + 3] = v.w;
        });
    }
    __syncthreads();

    // ---- chunk 1: rows 16..31 ----
    static_for<8>([&](auto J) {
        constexpr int j = J.value;
        tile[(2 * j + (lane >> 5)) * 33 + (lane & 31)] = B[j];
    });
    __syncthreads();
    if (t >= 16) {
        static_for<16>([&](auto J) {
            constexpr int j = J.value;
            const float4 v = tile[(t - 16) * 33 + h * 16 + j];
            st[4 * j + 0] = v.x; st[4 * j + 1] = v.y;
            st[4 * j + 2] = v.z; st[4 * j + 3] = v.w;
        });
    }

    // ---- squared norm of full row, 4-way split chains ----
    float s0 = 0.f, s1 = 0.f, s2 = 0.f, s3 = 0.f;
    static_for<16>([&](auto I) {
        constexpr int i = I.value;
        s0 = fmaf(st[4 * i + 0], st[4 * i + 0], s0);
        s1 = fmaf(st[4 * i + 1], st[4 * i + 1], s1);
        s2 = fmaf(st[4 * i + 2], st[4 * i + 2], s2);
        s3 = fmaf(st[4 * i + 3], st[4 * i + 3], s3);
    });
    float ss = (s0 + s1) + (s2 + s3);
    ss += swap_adj(ss);

    // ---- 2 layers of 7 RY gates; CZ folded algebraically ----
    static_for<2>([&](auto D) {
        constexpr int d = D.value;
        // q = 0..5: pairs stay within the lane's half
        static_for<6>([&](auto Q) {
            constexpr int q = Q.value;
            const float ha = 0.5f * theta[d * NQ + q];
            const float c_ = __cosf(ha), s_ = __sinf(ha);
            // layer-2 q5 absorbs the (-1)^(b5*h) CZ cross term
            const float sA = (d == 1 && q == 5) ? s_ * hs : s_;
            const float cA = (d == 1 && q == 5) ? c_ * hs : c_;
            static_for<32>([&](auto P) {
                constexpr int p  = P.value;
                constexpr int lo = 1 << q;
                constexpr int i0 = ((p >> q) << (q + 1)) | (p & (lo - 1));
                constexpr int i1 = i0 | lo;
                // layer-2 q0 absorbs layer-1 CZ local signs (compile-time fneg)
                constexpr bool n0 = (d == 1 && q == 0) &&
                                    (__builtin_popcount(i0 & (i0 >> 1)) & 1);
                constexpr bool n1 = (d == 1 && q == 0) &&
                                    (__builtin_popcount(i1 & (i1 >> 1)) & 1);
                const float a0 = n0 ? -st[i0] : st[i0];
                const float a1 = n1 ? -st[i1] : st[i1];
                st[i0] = fmaf(c_, a0, -sA * a1);
                st[i1] = fmaf(s_, a0,  cA * a1);
            });
        });
        // q = 6: partner lane holds the other half-row
        {
            const float ha = 0.5f * theta[d * NQ + 6];
            const float c_ = __cosf(ha), s_ = __sinf(ha);
            const float sgn = h ? s_ : -s_;   // h=0: c*a0-s*a1 ; h=1: s*a0+c*a1
            static_for<HALF>([&](auto J) {
                constexpr int j = J.value;
                const float other = swap_adj(st[j]);
                st[j] = fmaf(sgn, other, c_ * st[j]);
            });
        }
        // layer-2 CZ: squared away by probs -> omitted entirely
    });

    // ---- probs (unnormalized) ----
    static_for<HALF>([&](auto J) {
        constexpr int j = J.value;
        st[j] *= st[j];
    });

    // ---- Walsh: local halving tree (k=0..5), cross-lane combine ----
    float o[NQ];
    static_for<6>([&](auto K) {
        constexpr int k = K.value;
        constexpr int n = HALF >> (k + 1);
        float acc = 0.f;
        static_for<32>([&](auto I) {
            constexpr int i = I.value;
            if constexpr (i < n) {
                const float a = st[2 * i], b = st[2 * i + 1];
                acc += a - b;
                st[i] = a + b;       // write idx i <= read idx 2i: safe
            }
        });
        o[k] = acc;
    });
    static_for<6>([&](auto K) {
        constexpr int k = K.value;
        o[k] += swap_adj(o[k]);                 // sum both halves
    });
    {
        const float part = st[0];               // sum of local probs
        o[6] = hs * (part - swap_adj(part));    // = part(h=0) - part(h=1)
    }
    const float invss = __builtin_amdgcn_rcpf(ss);
    static_for<NQ>([&](auto K) { o[K.value] *= invss; });

    // ---- repack through LDS for coalesced stores (224 floats/block) ----
    __syncthreads();
    float* ldsf = reinterpret_cast<float*>(tile);
    if (h == 0) {
        static_for<NQ>([&](auto K) {
            constexpr int k = K.value;
            ldsf[t * NQ + k] = o[k];
        });
    }
    __syncthreads();
    float* __restrict__ ob = out + (size_t)blockIdx.x * (RPB * NQ);
    static_for<4>([&](auto It) {
        constexpr int it = It.value;
        const int idx = it * 64 + lane;
        if constexpr (it < 3) {
            ob[idx] = ldsf[idx];
        } else {
            if (idx < RPB * NQ) ob[idx] = ldsf[idx];
        }
    });
}

extern "C" void kernel_launch(void* const* d_in, const int* in_sizes, int n_in,
                              void* d_out, int out_size, void* d_ws, size_t ws_size,
                              hipStream_t stream)
{
    const float* embed = (const float*)d_in[0];
    const float* theta = (const float*)d_in[1];
    float* out = (float*)d_out;
    const int batch = in_sizes[0] / DIM;          // 262144
    dim3 grid(batch / RPB), block(64);
    hipLaunchKernelGGL(qnat_kernel, grid, block, 0, stream, embed, theta, out);
}